// Round 12
// baseline (209.678 us; speedup 1.0000x reference)
//
#include <hip/hip_runtime.h>
#include <hip/hip_bf16.h>

constexpr int KNB = 16;  // neighbors (K)
constexpr int HH  = 4;   // heads
constexpr int DD  = 32;  // head dim
constexpr int WPB   = 2; // waves per 128-thread block (small blocks -> high residency)
constexpr int ITERS = 4; // nodes (n) per wave

typedef __attribute__((ext_vector_type(4))) float f32x4;
typedef __attribute__((ext_vector_type(8))) short bf16x8;
union BFRAG { bf16x8 v; unsigned u[4]; };

// packed RNE f32x2 -> bf16x2 (compiler emits v_cvt_pk_bf16_f32)
__device__ __forceinline__ unsigned pk_bf16(float a, float b) {
    union { __hip_bfloat162 b2; unsigned u; } r;
    r.b2 = __float22bfloat162_rn(make_float2(a, b));
    return r.u;
}
__device__ __forceinline__ float2 unpk_bf16(unsigned u) {
    union { unsigned u; __hip_bfloat162 b2; } r; r.u = u;
    return make_float2(__bfloat162float(r.b2.x), __bfloat162float(r.b2.y));
}

// R7's verified structure (node-merged load batch, hi/lo bf16 MFMA Linear,
// shuffle LN, max-free softmax) with ONE variable changed: true occupancy.
// 128-thread blocks + __launch_bounds__(128,8) target 16 workgroups/CU =
// 32 waves/CU (vs ~13 in R4-R11). TLP is the only latency-hiding mechanism
// the compiler has consistently honored across this series.
template<bool GUARD>
__global__ __launch_bounds__(128, 8) void geoneigh_occ(
    const float* __restrict__ q, const float* __restrict__ kn,
    const float* __restrict__ vn, const float* __restrict__ geo,
    const float* __restrict__ W, const float* __restrict__ bvec,
    const float* __restrict__ gamma, const float* __restrict__ beta,
    float* __restrict__ out, int nN, int strideN)
{
    const int l   = threadIdx.x & 63;
    const int gw0 = __builtin_amdgcn_readfirstlane(
                        blockIdx.x * WPB + (threadIdx.x >> 6));

    const int lm = l & 15;   // edge (A/C row) / e-low (B col)
    const int lg = l >> 4;   // k-group for A/B frags; edge-block for C

    const float SC    = 5.656854249492381f;   // sqrt(32), folded into W
    const float LOG2E = 1.4426950408889634f;  // folded into gamma/beta

    // ---- once per wave: B operand (SC*W) hi/lo; lane = W[e=lm+16t][d=lg*8+j]
    BFRAG Wh[2], Wl[2];
    #pragma unroll
    for (int t = 0; t < 2; ++t) {
        const float* wr = &W[(t * 16 + lm) * DD + lg * 8];
        const float4 wa = *(const float4*)wr;
        const float4 wb = *(const float4*)(wr + 4);
        float wf[8] = {wa.x * SC, wa.y * SC, wa.z * SC, wa.w * SC,
                       wb.x * SC, wb.y * SC, wb.z * SC, wb.w * SC};
        #pragma unroll
        for (int p = 0; p < 4; ++p) {
            const unsigned h = pk_bf16(wf[2 * p], wf[2 * p + 1]);
            const float2 hr = unpk_bf16(h);
            Wh[t].u[p] = h;
            Wl[t].u[p] = pk_bf16(wf[2 * p] - hr.x, wf[2 * p + 1] - hr.y);
        }
    }
    float bias[2], gamL[2], betL[2];
    #pragma unroll
    for (int t = 0; t < 2; ++t) {
        bias[t] = bvec[lm + 16 * t];
        gamL[t] = gamma[lm + 16 * t] * LOG2E;
        betL[t] = beta[lm + 16 * t] * LOG2E;
    }

    // loop-invariant lane offsets (elements)
    const int koff = lm * (HH * DD) + lg * 8;   // + h*DD per head
    const int goff = lm * DD + lg * 8;
    const int qoff = lg * 8;                    // + h*DD per head
    const int voff = (lg * 4) * (HH * DD) + lm; // + r*(HH*DD) + h*DD + 16t

    #pragma unroll
    for (int it = 0; it < ITERS; ++it) {
        const int n = gw0 + it * strideN;
        if (GUARD && n >= nN) break;  // wave-uniform, increasing
        const size_t nb = (size_t)n;

        const float* gb = geo + nb * (KNB * DD) + goff;
        const float* kb = kn  + nb * (KNB * HH * DD) + koff;
        const float* qb = q   + nb * (HH * DD) + qoff;
        const float* vb = vn  + nb * (KNB * HH * DD) + voff;

        // ---- one load batch for the whole node ----
        const float4 gf0 = *(const float4*)gb;
        const float4 gf1 = *(const float4*)(gb + 4);
        float4 kf[4][2], qf[4][2];
        #pragma unroll
        for (int h = 0; h < 4; ++h) {
            kf[h][0] = *(const float4*)(kb + h * DD);
            kf[h][1] = *(const float4*)(kb + h * DD + 4);
            qf[h][0] = *(const float4*)(qb + h * DD);
            qf[h][1] = *(const float4*)(qb + h * DD + 4);
        }
        float vr[4][2][4];  // [h][e-half][r]
        #pragma unroll
        for (int h = 0; h < 4; ++h)
            #pragma unroll
            for (int t = 0; t < 2; ++t)
                #pragma unroll
                for (int r = 0; r < 4; ++r)
                    vr[h][t][r] = vb[r * (HH * DD) + h * DD + 16 * t];

        // ---- two h-pair units per node ----
        #pragma unroll
        for (int hp = 0; hp < 2; ++hp) {
            // w = q - k + geo; hi/lo split; MFMA
            f32x4 acc[2][2];
            #pragma unroll
            for (int u = 0; u < 2; ++u) {
                const int h = hp * 2 + u;
                float wv[8];
                #pragma unroll
                for (int p = 0; p < 2; ++p) {
                    const float4 kq = kf[h][p], qq = qf[h][p];
                    const float4 gg = p ? gf1 : gf0;
                    wv[4 * p + 0] = qq.x - kq.x + gg.x;
                    wv[4 * p + 1] = qq.y - kq.y + gg.y;
                    wv[4 * p + 2] = qq.z - kq.z + gg.z;
                    wv[4 * p + 3] = qq.w - kq.w + gg.w;
                }
                BFRAG Ah, Al;
                #pragma unroll
                for (int p = 0; p < 4; ++p) {
                    const unsigned hh = pk_bf16(wv[2 * p], wv[2 * p + 1]);
                    const float2 hr = unpk_bf16(hh);
                    Ah.u[p] = hh;
                    Al.u[p] = pk_bf16(wv[2 * p] - hr.x, wv[2 * p + 1] - hr.y);
                }
                #pragma unroll
                for (int t = 0; t < 2; ++t) {
                    f32x4 c = {bias[t], bias[t], bias[t], bias[t]};
                    c = __builtin_amdgcn_mfma_f32_16x16x32_bf16(Ah.v, Wh[t].v, c, 0, 0, 0);
                    c = __builtin_amdgcn_mfma_f32_16x16x32_bf16(Ah.v, Wl[t].v, c, 0, 0, 0);
                    c = __builtin_amdgcn_mfma_f32_16x16x32_bf16(Al.v, Wh[t].v, c, 0, 0, 0);
                    acc[u][t] = c;
                }
            }

            // epilogue: ReLU+LN (over e), softmax-no-max (over k), PV
            // C layout: lane holds C[edge=lg*4+r][e=lm+16t]
            float outv[2], sumv[2];
            #pragma unroll
            for (int u = 0; u < 2; ++u) {
                const int h = hp * 2 + u;
                float x[2][4], t1[4], t2[4];
                #pragma unroll
                for (int t = 0; t < 2; ++t)
                    #pragma unroll
                    for (int r = 0; r < 4; ++r)
                        x[t][r] = fmaxf(acc[u][t][r], 0.f);  // bias in acc
                #pragma unroll
                for (int r = 0; r < 4; ++r) {
                    t1[r] = x[0][r] + x[1][r];
                    t2[r] = x[0][r] * x[0][r] + x[1][r] * x[1][r];
                }
                #pragma unroll
                for (int m = 1; m <= 8; m <<= 1) {
                    #pragma unroll
                    for (int r = 0; r < 4; ++r) {
                        t1[r] += __shfl_xor(t1[r], m);
                        t2[r] += __shfl_xor(t2[r], m);
                    }
                }
                float z[2][4];
                #pragma unroll
                for (int r = 0; r < 4; ++r) {
                    const float mu  = t1[r] * 0.03125f;
                    const float var = fmaxf(t2[r] * 0.03125f - mu * mu, 0.f);
                    const float inv = rsqrtf(var + 1e-5f);
                    #pragma unroll
                    for (int t = 0; t < 2; ++t)
                        z[t][r] = (x[t][r] - mu) * inv * gamL[t] + betL[t];
                }
                float S[2], o[2];
                #pragma unroll
                for (int t = 0; t < 2; ++t) {
                    float s = 0.f, oo = 0.f;
                    #pragma unroll
                    for (int r = 0; r < 4; ++r) {
                        const float p = exp2f(z[t][r]);  // e^orig, log2e folded
                        s += p;
                        oo = fmaf(p, vr[h][t][r], oo);
                    }
                    s  += __shfl_xor(s, 16);
                    s  += __shfl_xor(s, 32);
                    oo += __shfl_xor(oo, 16);
                    oo += __shfl_xor(oo, 32);
                    S[t] = s; o[t] = oo;
                }
                const int sel = lg & 1;  // e bit4 of this lane's column
                outv[u] = sel ? o[1] : o[0];
                sumv[u] = sel ? S[1] : S[0];
            }

            // contiguous 256B full-wave store: lane l -> (h=hp*2+(l>>5), e=l&31)
            const int us = l >> 5;
            const float oo = us ? outv[1] : outv[0];
            const float ss = us ? sumv[1] : sumv[0];
            out[(nb * HH + hp * 2 + us) * DD + (l & 31)] = __fdividef(oo, ss);
        }
    }
}

extern "C" void kernel_launch(void* const* d_in, const int* in_sizes, int n_in,
                              void* d_out, int out_size, void* d_ws, size_t ws_size,
                              hipStream_t stream) {
    const float* q   = (const float*)d_in[0];
    const float* kn  = (const float*)d_in[1];
    const float* vn  = (const float*)d_in[2];
    const float* geo = (const float*)d_in[3];
    const float* W   = (const float*)d_in[4];
    const float* b   = (const float*)d_in[5];
    const float* gam = (const float*)d_in[6];
    const float* bet = (const float*)d_in[7];
    float* out = (float*)d_out;

    const int BN      = in_sizes[0] / (HH * DD);  // B*N nodes
    const int blocks  = (BN + WPB * ITERS - 1) / (WPB * ITERS);
    const int strideN = blocks * WPB;
    const bool exact  = (BN == blocks * WPB * ITERS);

    if (exact)
        hipLaunchKernelGGL(geoneigh_occ<false>, dim3(blocks), dim3(128), 0,
                           stream, q, kn, vn, geo, W, b, gam, bet, out,
                           BN, strideN);
    else
        hipLaunchKernelGGL(geoneigh_occ<true>, dim3(blocks), dim3(128), 0,
                           stream, q, kn, vn, geo, W, b, gam, bet, out,
                           BN, strideN);
}

// Round 13
// 126.234 us; speedup vs baseline: 1.6610x; 1.6610x over previous
//
#include <hip/hip_runtime.h>
#include <hip/hip_bf16.h>

constexpr int KNB = 16;  // neighbors (K)
constexpr int HH  = 4;   // heads
constexpr int DD  = 32;  // head dim
constexpr int WPB = 4;   // waves per 256-thread block; 1 node per wave

typedef __attribute__((ext_vector_type(4))) float f32x4;
typedef __attribute__((ext_vector_type(8))) short bf16x8;
union BFRAG { bf16x8 v; unsigned u[4]; };

// packed RNE f32x2 -> bf16x2 (compiler emits v_cvt_pk_bf16_f32)
__device__ __forceinline__ unsigned pk_bf16(float a, float b) {
    union { __hip_bfloat162 b2; unsigned u; } r;
    r.b2 = __float22bfloat162_rn(make_float2(a, b));
    return r.u;
}
__device__ __forceinline__ float2 unpk_bf16(unsigned u) {
    union { unsigned u; __hip_bfloat162 b2; } r; r.u = u;
    return make_float2(__bfloat162float(r.b2.x), __bfloat162float(r.b2.y));
}

// R7's verified structure (node-merged load batch, hi/lo bf16 MFMA Linear,
// shuffle LN, max-free softmax) with ONE variable changed vs R7: grid-level
// TLP. ITERS=1, 2048 blocks x 4 waves = 8192 waves = nominal 8 waves/SIMD
// (R5/R7 launched only 4096 waves -> grid-capped ~50% occupancy).
// __launch_bounds__(256,6) caps VGPR at 85; R7's body needed 64, so no
// spill (R12's failure mode; check WRITE_SIZE==8MB).
template<bool GUARD>
__global__ __launch_bounds__(256, 6) void geoneigh_tlp(
    const float* __restrict__ q, const float* __restrict__ kn,
    const float* __restrict__ vn, const float* __restrict__ geo,
    const float* __restrict__ W, const float* __restrict__ bvec,
    const float* __restrict__ gamma, const float* __restrict__ beta,
    float* __restrict__ out, int nN)
{
    const int l = threadIdx.x & 63;
    const int n = __builtin_amdgcn_readfirstlane(
                      blockIdx.x * WPB + (threadIdx.x >> 6));
    if (GUARD && n >= nN) return;

    const int lm = l & 15;   // edge (A/C row) / e-low (B col)
    const int lg = l >> 4;   // k-group for A/B frags; edge-block for C

    const float SC    = 5.656854249492381f;   // sqrt(32), folded into W
    const float LOG2E = 1.4426950408889634f;  // folded into gamma/beta

    // ---- B operand (SC*W) hi/lo; lane = W[e=lm+16t][d=lg*8+j] ----
    BFRAG Wh[2], Wl[2];
    #pragma unroll
    for (int t = 0; t < 2; ++t) {
        const float* wr = &W[(t * 16 + lm) * DD + lg * 8];
        const float4 wa = *(const float4*)wr;
        const float4 wb = *(const float4*)(wr + 4);
        float wf[8] = {wa.x * SC, wa.y * SC, wa.z * SC, wa.w * SC,
                       wb.x * SC, wb.y * SC, wb.z * SC, wb.w * SC};
        #pragma unroll
        for (int p = 0; p < 4; ++p) {
            const unsigned h = pk_bf16(wf[2 * p], wf[2 * p + 1]);
            const float2 hr = unpk_bf16(h);
            Wh[t].u[p] = h;
            Wl[t].u[p] = pk_bf16(wf[2 * p] - hr.x, wf[2 * p + 1] - hr.y);
        }
    }
    float bias[2], gamL[2], betL[2];
    #pragma unroll
    for (int t = 0; t < 2; ++t) {
        bias[t] = bvec[lm + 16 * t];
        gamL[t] = gamma[lm + 16 * t] * LOG2E;
        betL[t] = beta[lm + 16 * t] * LOG2E;
    }

    const size_t nb = (size_t)n;
    const float* gb = geo + nb * (KNB * DD) + lm * DD + lg * 8;
    const float* kb = kn  + nb * (KNB * HH * DD) + lm * (HH * DD) + lg * 8;
    const float* qb = q   + nb * (HH * DD) + lg * 8;
    const float* vb = vn  + nb * (KNB * HH * DD) + (lg * 4) * (HH * DD) + lm;

    // ---- one load batch for the whole node ----
    const float4 gf0 = *(const float4*)gb;
    const float4 gf1 = *(const float4*)(gb + 4);
    float4 kf[4][2], qf[4][2];
    #pragma unroll
    for (int h = 0; h < 4; ++h) {
        kf[h][0] = *(const float4*)(kb + h * DD);
        kf[h][1] = *(const float4*)(kb + h * DD + 4);
        qf[h][0] = *(const float4*)(qb + h * DD);
        qf[h][1] = *(const float4*)(qb + h * DD + 4);
    }
    float vr[4][2][4];  // [h][e-half][r]
    #pragma unroll
    for (int h = 0; h < 4; ++h)
        #pragma unroll
        for (int t = 0; t < 2; ++t)
            #pragma unroll
            for (int r = 0; r < 4; ++r)
                vr[h][t][r] = vb[r * (HH * DD) + h * DD + 16 * t];

    // ---- two h-pair units per node ----
    #pragma unroll
    for (int hp = 0; hp < 2; ++hp) {
        f32x4 acc[2][2];
        #pragma unroll
        for (int u = 0; u < 2; ++u) {
            const int h = hp * 2 + u;
            float wv[8];
            #pragma unroll
            for (int p = 0; p < 2; ++p) {
                const float4 kq = kf[h][p], qq = qf[h][p];
                const float4 gg = p ? gf1 : gf0;
                wv[4 * p + 0] = qq.x - kq.x + gg.x;
                wv[4 * p + 1] = qq.y - kq.y + gg.y;
                wv[4 * p + 2] = qq.z - kq.z + gg.z;
                wv[4 * p + 3] = qq.w - kq.w + gg.w;
            }
            BFRAG Ah, Al;
            #pragma unroll
            for (int p = 0; p < 4; ++p) {
                const unsigned hh = pk_bf16(wv[2 * p], wv[2 * p + 1]);
                const float2 hr = unpk_bf16(hh);
                Ah.u[p] = hh;
                Al.u[p] = pk_bf16(wv[2 * p] - hr.x, wv[2 * p + 1] - hr.y);
            }
            #pragma unroll
            for (int t = 0; t < 2; ++t) {
                f32x4 c = {bias[t], bias[t], bias[t], bias[t]};
                c = __builtin_amdgcn_mfma_f32_16x16x32_bf16(Ah.v, Wh[t].v, c, 0, 0, 0);
                c = __builtin_amdgcn_mfma_f32_16x16x32_bf16(Ah.v, Wl[t].v, c, 0, 0, 0);
                c = __builtin_amdgcn_mfma_f32_16x16x32_bf16(Al.v, Wh[t].v, c, 0, 0, 0);
                acc[u][t] = c;
            }
        }

        // epilogue: ReLU+LN (over e), softmax-no-max (over k), PV
        float outv[2], sumv[2];
        #pragma unroll
        for (int u = 0; u < 2; ++u) {
            const int h = hp * 2 + u;
            float x[2][4], t1[4], t2[4];
            #pragma unroll
            for (int t = 0; t < 2; ++t)
                #pragma unroll
                for (int r = 0; r < 4; ++r)
                    x[t][r] = fmaxf(acc[u][t][r], 0.f);  // bias in acc
            #pragma unroll
            for (int r = 0; r < 4; ++r) {
                t1[r] = x[0][r] + x[1][r];
                t2[r] = x[0][r] * x[0][r] + x[1][r] * x[1][r];
            }
            #pragma unroll
            for (int m = 1; m <= 8; m <<= 1) {
                #pragma unroll
                for (int r = 0; r < 4; ++r) {
                    t1[r] += __shfl_xor(t1[r], m);
                    t2[r] += __shfl_xor(t2[r], m);
                }
            }
            float z[2][4];
            #pragma unroll
            for (int r = 0; r < 4; ++r) {
                const float mu  = t1[r] * 0.03125f;
                const float var = fmaxf(t2[r] * 0.03125f - mu * mu, 0.f);
                const float inv = rsqrtf(var + 1e-5f);
                #pragma unroll
                for (int t = 0; t < 2; ++t)
                    z[t][r] = (x[t][r] - mu) * inv * gamL[t] + betL[t];
            }
            float S[2], o[2];
            #pragma unroll
            for (int t = 0; t < 2; ++t) {
                float s = 0.f, oo = 0.f;
                #pragma unroll
                for (int r = 0; r < 4; ++r) {
                    const float p = exp2f(z[t][r]);  // e^orig, log2e folded
                    s += p;
                    oo = fmaf(p, vr[h][t][r], oo);
                }
                s  += __shfl_xor(s, 16);
                s  += __shfl_xor(s, 32);
                oo += __shfl_xor(oo, 16);
                oo += __shfl_xor(oo, 32);
                S[t] = s; o[t] = oo;
            }
            const int sel = lg & 1;  // e bit4 of this lane's column
            outv[u] = sel ? o[1] : o[0];
            sumv[u] = sel ? S[1] : S[0];
        }

        // contiguous 256B full-wave store: lane l -> (h=hp*2+(l>>5), e=l&31)
        const int us = l >> 5;
        const float oo = us ? outv[1] : outv[0];
        const float ss = us ? sumv[1] : sumv[0];
        out[(nb * HH + hp * 2 + us) * DD + (l & 31)] = __fdividef(oo, ss);
    }
}

extern "C" void kernel_launch(void* const* d_in, const int* in_sizes, int n_in,
                              void* d_out, int out_size, void* d_ws, size_t ws_size,
                              hipStream_t stream) {
    const float* q   = (const float*)d_in[0];
    const float* kn  = (const float*)d_in[1];
    const float* vn  = (const float*)d_in[2];
    const float* geo = (const float*)d_in[3];
    const float* W   = (const float*)d_in[4];
    const float* b   = (const float*)d_in[5];
    const float* gam = (const float*)d_in[6];
    const float* bet = (const float*)d_in[7];
    float* out = (float*)d_out;

    const int BN     = in_sizes[0] / (HH * DD);  // B*N nodes
    const int blocks = (BN + WPB - 1) / WPB;
    const bool exact = (BN == blocks * WPB);

    if (exact)
        hipLaunchKernelGGL(geoneigh_tlp<false>, dim3(blocks), dim3(256), 0,
                           stream, q, kn, vn, geo, W, b, gam, bet, out, BN);
    else
        hipLaunchKernelGGL(geoneigh_tlp<true>, dim3(blocks), dim3(256), 0,
                           stream, q, kn, vn, geo, W, b, gam, bet, out, BN);
}

// Round 14
// 61.655 us; speedup vs baseline: 3.4008x; 2.0474x over previous
//
#include <hip/hip_runtime.h>
#include <hip/hip_bf16.h>

constexpr int KNB = 16;  // neighbors (K)
constexpr int HH  = 4;   // heads
constexpr int DD  = 32;  // head dim
constexpr int WPB   = 4; // waves per 256-thread block
constexpr int ITERS = 2; // nodes (n) per wave  (8192 waves = full machine)

typedef __attribute__((ext_vector_type(4))) float f32x4;
typedef __attribute__((ext_vector_type(8))) short bf16x8;
union BFRAG { bf16x8 v; unsigned u[4]; };

// packed RNE f32x2 -> bf16x2 (compiler emits v_cvt_pk_bf16_f32)
__device__ __forceinline__ unsigned pk_bf16(float a, float b) {
    union { __hip_bfloat162 b2; unsigned u; } r;
    r.b2 = __float22bfloat162_rn(make_float2(a, b));
    return r.u;
}
__device__ __forceinline__ float2 unpk_bf16(unsigned u) {
    union { unsigned u; __hip_bfloat162 b2; } r; r.u = u;
    return make_float2(__bfloat162float(r.b2.x), __bfloat162float(r.b2.y));
}

// R7's verified kernel (node-merged load batch, hi/lo bf16 MFMA Linear,
// shuffle LN, max-free softmax; (256,4) -> 64 VGPR clean) + ONE change:
// a staggered-start prologue. Theory: dur 62us == 48us memory + 14us
// compute SERIALIZED because all waves run the same phase simultaneously
// (generation lock). Sleeping each wave by (blockIdx&7)*4+waveId sleep
// quanta (~64cy each, 0..2000cy) spreads the phases so some waves always
// occupy the memory system while others compute.
template<bool GUARD>
__global__ __launch_bounds__(256, 4) void geoneigh_skew(
    const float* __restrict__ q, const float* __restrict__ kn,
    const float* __restrict__ vn, const float* __restrict__ geo,
    const float* __restrict__ W, const float* __restrict__ bvec,
    const float* __restrict__ gamma, const float* __restrict__ beta,
    float* __restrict__ out, int nN, int strideN)
{
    const int l   = threadIdx.x & 63;
    const int gw0 = __builtin_amdgcn_readfirstlane(
                        blockIdx.x * WPB + (threadIdx.x >> 6));

    // ---- phase-decoherence stagger: 0..31 quanta of ~64cy ----
    {
        const int skew = __builtin_amdgcn_readfirstlane(
            ((blockIdx.x & 7) << 2) | (threadIdx.x >> 6));
        for (int i = 0; i < skew; ++i) __builtin_amdgcn_s_sleep(1);
    }

    const int lm = l & 15;   // edge (A/C row) / e-low (B col)
    const int lg = l >> 4;   // k-group for A/B frags; edge-block for C

    const float SC    = 5.656854249492381f;   // sqrt(32), folded into W
    const float LOG2E = 1.4426950408889634f;  // folded into gamma/beta

    // ---- once per wave: B operand (SC*W) hi/lo; lane = W[e=lm+16t][d=lg*8+j]
    BFRAG Wh[2], Wl[2];
    #pragma unroll
    for (int t = 0; t < 2; ++t) {
        const float* wr = &W[(t * 16 + lm) * DD + lg * 8];
        const float4 wa = *(const float4*)wr;
        const float4 wb = *(const float4*)(wr + 4);
        float wf[8] = {wa.x * SC, wa.y * SC, wa.z * SC, wa.w * SC,
                       wb.x * SC, wb.y * SC, wb.z * SC, wb.w * SC};
        #pragma unroll
        for (int p = 0; p < 4; ++p) {
            const unsigned h = pk_bf16(wf[2 * p], wf[2 * p + 1]);
            const float2 hr = unpk_bf16(h);
            Wh[t].u[p] = h;
            Wl[t].u[p] = pk_bf16(wf[2 * p] - hr.x, wf[2 * p + 1] - hr.y);
        }
    }
    float bias[2], gamL[2], betL[2];
    #pragma unroll
    for (int t = 0; t < 2; ++t) {
        bias[t] = bvec[lm + 16 * t];
        gamL[t] = gamma[lm + 16 * t] * LOG2E;
        betL[t] = beta[lm + 16 * t] * LOG2E;
    }

    // loop-invariant lane offsets (elements)
    const int koff = lm * (HH * DD) + lg * 8;   // + h*DD per head
    const int goff = lm * DD + lg * 8;
    const int qoff = lg * 8;                    // + h*DD per head
    const int voff = (lg * 4) * (HH * DD) + lm; // + r*(HH*DD) + h*DD + 16t

    #pragma unroll
    for (int it = 0; it < ITERS; ++it) {
        const int n = gw0 + it * strideN;
        if (GUARD && n >= nN) break;  // wave-uniform, increasing
        const size_t nb = (size_t)n;

        const float* gb = geo + nb * (KNB * DD) + goff;
        const float* kb = kn  + nb * (KNB * HH * DD) + koff;
        const float* qb = q   + nb * (HH * DD) + qoff;
        const float* vb = vn  + nb * (KNB * HH * DD) + voff;

        // ---- one big load batch for the whole node ----
        const float4 gf0 = *(const float4*)gb;
        const float4 gf1 = *(const float4*)(gb + 4);
        float4 kf[4][2], qf[4][2];
        #pragma unroll
        for (int h = 0; h < 4; ++h) {
            kf[h][0] = *(const float4*)(kb + h * DD);
            kf[h][1] = *(const float4*)(kb + h * DD + 4);
            qf[h][0] = *(const float4*)(qb + h * DD);
            qf[h][1] = *(const float4*)(qb + h * DD + 4);
        }
        float vr[4][2][4];  // [h][e-half][r]
        #pragma unroll
        for (int h = 0; h < 4; ++h)
            #pragma unroll
            for (int t = 0; t < 2; ++t)
                #pragma unroll
                for (int r = 0; r < 4; ++r)
                    vr[h][t][r] = vb[r * (HH * DD) + h * DD + 16 * t];

        // ---- two h-pair units per node ----
        #pragma unroll
        for (int hp = 0; hp < 2; ++hp) {
            f32x4 acc[2][2];
            #pragma unroll
            for (int u = 0; u < 2; ++u) {
                const int h = hp * 2 + u;
                float wv[8];
                #pragma unroll
                for (int p = 0; p < 2; ++p) {
                    const float4 kq = kf[h][p], qq = qf[h][p];
                    const float4 gg = p ? gf1 : gf0;
                    wv[4 * p + 0] = qq.x - kq.x + gg.x;
                    wv[4 * p + 1] = qq.y - kq.y + gg.y;
                    wv[4 * p + 2] = qq.z - kq.z + gg.z;
                    wv[4 * p + 3] = qq.w - kq.w + gg.w;
                }
                BFRAG Ah, Al;
                #pragma unroll
                for (int p = 0; p < 4; ++p) {
                    const unsigned hh = pk_bf16(wv[2 * p], wv[2 * p + 1]);
                    const float2 hr = unpk_bf16(hh);
                    Ah.u[p] = hh;
                    Al.u[p] = pk_bf16(wv[2 * p] - hr.x, wv[2 * p + 1] - hr.y);
                }
                #pragma unroll
                for (int t = 0; t < 2; ++t) {
                    f32x4 c = {bias[t], bias[t], bias[t], bias[t]};
                    c = __builtin_amdgcn_mfma_f32_16x16x32_bf16(Ah.v, Wh[t].v, c, 0, 0, 0);
                    c = __builtin_amdgcn_mfma_f32_16x16x32_bf16(Ah.v, Wl[t].v, c, 0, 0, 0);
                    c = __builtin_amdgcn_mfma_f32_16x16x32_bf16(Al.v, Wh[t].v, c, 0, 0, 0);
                    acc[u][t] = c;
                }
            }

            // epilogue: ReLU+LN (over e), softmax-no-max (over k), PV
            // C layout: lane holds C[edge=lg*4+r][e=lm+16t]
            float outv[2], sumv[2];
            #pragma unroll
            for (int u = 0; u < 2; ++u) {
                const int h = hp * 2 + u;
                float x[2][4], t1[4], t2[4];
                #pragma unroll
                for (int t = 0; t < 2; ++t)
                    #pragma unroll
                    for (int r = 0; r < 4; ++r)
                        x[t][r] = fmaxf(acc[u][t][r], 0.f);  // bias in acc
                #pragma unroll
                for (int r = 0; r < 4; ++r) {
                    t1[r] = x[0][r] + x[1][r];
                    t2[r] = x[0][r] * x[0][r] + x[1][r] * x[1][r];
                }
                #pragma unroll
                for (int m = 1; m <= 8; m <<= 1) {
                    #pragma unroll
                    for (int r = 0; r < 4; ++r) {
                        t1[r] += __shfl_xor(t1[r], m);
                        t2[r] += __shfl_xor(t2[r], m);
                    }
                }
                float z[2][4];
                #pragma unroll
                for (int r = 0; r < 4; ++r) {
                    const float mu  = t1[r] * 0.03125f;
                    const float var = fmaxf(t2[r] * 0.03125f - mu * mu, 0.f);
                    const float inv = rsqrtf(var + 1e-5f);
                    #pragma unroll
                    for (int t = 0; t < 2; ++t)
                        z[t][r] = (x[t][r] - mu) * inv * gamL[t] + betL[t];
                }
                float S[2], o[2];
                #pragma unroll
                for (int t = 0; t < 2; ++t) {
                    float s = 0.f, oo = 0.f;
                    #pragma unroll
                    for (int r = 0; r < 4; ++r) {
                        const float p = exp2f(z[t][r]);  // e^orig, log2e folded
                        s += p;
                        oo = fmaf(p, vr[h][t][r], oo);
                    }
                    s  += __shfl_xor(s, 16);
                    s  += __shfl_xor(s, 32);
                    oo += __shfl_xor(oo, 16);
                    oo += __shfl_xor(oo, 32);
                    S[t] = s; o[t] = oo;
                }
                const int sel = lg & 1;  // e bit4 of this lane's column
                outv[u] = sel ? o[1] : o[0];
                sumv[u] = sel ? S[1] : S[0];
            }

            // contiguous 256B full-wave store: lane l -> (h=hp*2+(l>>5), e=l&31)
            const int us = l >> 5;
            const float oo = us ? outv[1] : outv[0];
            const float ss = us ? sumv[1] : sumv[0];
            out[(nb * HH + hp * 2 + us) * DD + (l & 31)] = __fdividef(oo, ss);
        }
    }
}

extern "C" void kernel_launch(void* const* d_in, const int* in_sizes, int n_in,
                              void* d_out, int out_size, void* d_ws, size_t ws_size,
                              hipStream_t stream) {
    const float* q   = (const float*)d_in[0];
    const float* kn  = (const float*)d_in[1];
    const float* vn  = (const float*)d_in[2];
    const float* geo = (const float*)d_in[3];
    const float* W   = (const float*)d_in[4];
    const float* b   = (const float*)d_in[5];
    const float* gam = (const float*)d_in[6];
    const float* bet = (const float*)d_in[7];
    float* out = (float*)d_out;

    const int BN      = in_sizes[0] / (HH * DD);  // B*N nodes
    const int blocks  = (BN + WPB * ITERS - 1) / (WPB * ITERS);
    const int strideN = blocks * WPB;
    const bool exact  = (BN == blocks * WPB * ITERS);

    if (exact)
        hipLaunchKernelGGL(geoneigh_skew<false>, dim3(blocks), dim3(256), 0,
                           stream, q, kn, vn, geo, W, b, gam, bet, out,
                           BN, strideN);
    else
        hipLaunchKernelGGL(geoneigh_skew<true>, dim3(blocks), dim3(256), 0,
                           stream, q, kn, vn, geo, W, b, gam, bet, out,
                           BN, strideN);
}